// Round 1
// baseline (5597.458 us; speedup 1.0000x reference)
//
#include <hip/hip_runtime.h>

namespace {
constexpr int NN   = 10000;   // nodes
constexpr int NE   = 640000;  // edges
constexpr int INC  = 128;     // input channels
constexpr int HIDC = 256;     // hidden channels
constexpr int OUTC = 10;      // output channels
constexpr int NG   = 64;      // graphs
}

__global__ __launch_bounds__(256) void zero_kernel(float* __restrict__ p, int n) {
    int i = blockIdx.x * blockDim.x + threadIdx.x;
    if (i < n) p[i] = 0.0f;
}

__global__ __launch_bounds__(256) void copy4_kernel(const float4* __restrict__ s,
                                                    float4* __restrict__ d, int n4) {
    int i = blockIdx.x * blockDim.x + threadIdx.x;
    if (i < n4) d[i] = s[i];
}

// One edge handled by F/4 consecutive threads (coalesced float4 gather of the
// source row); accumulate into agg[dst] with hardware fp32 atomics.
template <int F>
__global__ __launch_bounds__(256) void scatter_kernel(const int* __restrict__ ei,
                                                      const float* __restrict__ ew,
                                                      const float* __restrict__ x,
                                                      float* __restrict__ agg) {
    constexpr int CH = F / 4;
    long long t = (long long)blockIdx.x * blockDim.x + threadIdx.x;
    int e = (int)(t / CH);
    int c = (int)(t % CH);
    if (e >= NE) return;
    int s = ei[e];
    int d = ei[NE + e];
    float w = ew[e];
    float4 v = ((const float4*)(x + (size_t)s * F))[c];
    float* dp = agg + (size_t)d * F + c * 4;
    unsafeAtomicAdd(dp + 0, w * v.x);
    unsafeAtomicAdd(dp + 1, w * v.y);
    unsafeAtomicAdd(dp + 2, w * v.z);
    unsafeAtomicAdd(dp + 3, w * v.w);
}

// C[M,256] = relu(A[M,K] @ W[256,K]^T + bias). 64x64 tile, TK=16, 4x4 microtile.
template <int K, bool RELU>
__global__ __launch_bounds__(256) void gemm_bias_kernel(const float* __restrict__ A,
                                                        const float* __restrict__ W,
                                                        const float* __restrict__ bias,
                                                        float* __restrict__ C, int M) {
    constexpr int TM = 64, TN = 64, TK = 16;
    __shared__ float As[TK][TM + 1];
    __shared__ float Bs[TK][TN + 1];
    const int tid = threadIdx.x;
    const int tx = tid & 15;       // 0..15 -> 4 cols each
    const int ty = tid >> 4;       // 0..15 -> 4 rows each
    const int bm = blockIdx.x * TM;
    const int bn = blockIdx.y * TN;
    const int lrow = tid >> 2;           // 0..63
    const int lk4  = (tid & 3) * 4;      // 0,4,8,12

    float acc[4][4] = {};

    for (int k0 = 0; k0 < K; k0 += TK) {
        // stage A tile (guarded on M edge)
        {
            int gm = bm + lrow;
            float4 v = make_float4(0.f, 0.f, 0.f, 0.f);
            if (gm < M) v = *(const float4*)(A + (size_t)gm * K + k0 + lk4);
            As[lk4 + 0][lrow] = v.x;
            As[lk4 + 1][lrow] = v.y;
            As[lk4 + 2][lrow] = v.z;
            As[lk4 + 3][lrow] = v.w;
        }
        // stage W tile (N=256 always full)
        {
            int gn = bn + lrow;
            float4 v = *(const float4*)(W + (size_t)gn * K + k0 + lk4);
            Bs[lk4 + 0][lrow] = v.x;
            Bs[lk4 + 1][lrow] = v.y;
            Bs[lk4 + 2][lrow] = v.z;
            Bs[lk4 + 3][lrow] = v.w;
        }
        __syncthreads();
#pragma unroll
        for (int kk = 0; kk < TK; kk++) {
            float a[4], b[4];
#pragma unroll
            for (int i = 0; i < 4; i++) a[i] = As[kk][ty * 4 + i];
#pragma unroll
            for (int j = 0; j < 4; j++) b[j] = Bs[kk][tx * 4 + j];
#pragma unroll
            for (int i = 0; i < 4; i++)
#pragma unroll
                for (int j = 0; j < 4; j++) acc[i][j] += a[i] * b[j];
        }
        __syncthreads();
    }

#pragma unroll
    for (int i = 0; i < 4; i++) {
        int m = bm + ty * 4 + i;
        if (m >= M) continue;
#pragma unroll
        for (int j = 0; j < 4; j++) {
            int n = bn + tx * 4 + j;
            float v = acc[i][j] + bias[n];
            if (RELU) v = fmaxf(v, 0.0f);
            C[(size_t)m * HIDC + n] = v;
        }
    }
}

__global__ __launch_bounds__(256) void pool_sum_kernel(const float* __restrict__ h,
                                                       const int* __restrict__ batch,
                                                       float* __restrict__ pooled,
                                                       float* __restrict__ cnt) {
    long long t = (long long)blockIdx.x * blockDim.x + threadIdx.x;
    int n = (int)(t >> 6);       // node
    int c = (int)(t & 63);       // float4 chunk of 256
    if (n >= NN) return;
    int g = batch[n];
    float4 v = ((const float4*)(h + (size_t)n * HIDC))[c];
    float* dp = pooled + (size_t)g * HIDC + c * 4;
    unsafeAtomicAdd(dp + 0, v.x);
    unsafeAtomicAdd(dp + 1, v.y);
    unsafeAtomicAdd(dp + 2, v.z);
    unsafeAtomicAdd(dp + 3, v.w);
    if (c == 0) unsafeAtomicAdd(&cnt[g], 1.0f);
}

__global__ __launch_bounds__(256) void head_kernel(const float* __restrict__ pooled,
                                                   const float* __restrict__ cnt,
                                                   const float* __restrict__ Wl,
                                                   const float* __restrict__ bl,
                                                   float* __restrict__ out) {
    __shared__ float s[HIDC];
    int g = blockIdx.x;
    float inv = 1.0f / fmaxf(cnt[g], 1.0f);
    s[threadIdx.x] = pooled[(size_t)g * HIDC + threadIdx.x] * inv;
    __syncthreads();
    if (threadIdx.x < OUTC) {
        int o = threadIdx.x;
        float acc = bl[o];
        for (int k = 0; k < HIDC; k++) acc += s[k] * Wl[(size_t)o * HIDC + k];
        out[(size_t)g * OUTC + o] = acc;
    }
}

extern "C" void kernel_launch(void* const* d_in, const int* in_sizes, int n_in,
                              void* d_out, int out_size, void* d_ws, size_t ws_size,
                              hipStream_t stream) {
    const float* x     = (const float*)d_in[0];
    const int*   ei    = (const int*)d_in[1];
    const int*   batch = (const int*)d_in[2];
    const float* ew    = (const float*)d_in[3];
    const float* W1    = (const float*)d_in[4];
    const float* b1    = (const float*)d_in[5];
    const float* W2    = (const float*)d_in[6];
    const float* b2    = (const float*)d_in[7];
    const float* W3    = (const float*)d_in[8];
    const float* b3    = (const float*)d_in[9];
    const float* Wl    = (const float*)d_in[10];
    const float* bl    = (const float*)d_in[11];

    float* A      = (float*)d_ws;                    // [NN, 256] (only NN*128 used for L1)
    float* B      = A + (size_t)NN * HIDC;           // [NN, 256]
    float* pooled = B + (size_t)NN * HIDC;           // [NG, 256]
    float* cnt    = pooled + (size_t)NG * HIDC;      // [NG]

    // zero pooled + cnt (contiguous)
    zero_kernel<<<(NG * HIDC + NG + 255) / 256, 256, 0, stream>>>(pooled, NG * HIDC + NG);

    dim3 gemm_grid((NN + 63) / 64, HIDC / 64);

    // ---- layer 1 (F=128) ----
    copy4_kernel<<<(NN * INC / 4 + 255) / 256, 256, 0, stream>>>(
        (const float4*)x, (float4*)A, NN * INC / 4);
    {
        long long tot = (long long)NE * (INC / 4);
        scatter_kernel<INC><<<(int)((tot + 255) / 256), 256, 0, stream>>>(ei, ew, x, A);
    }
    gemm_bias_kernel<INC, true><<<gemm_grid, 256, 0, stream>>>(A, W1, b1, B, NN);

    // ---- layer 2 (F=256) ----
    copy4_kernel<<<(NN * HIDC / 4 + 255) / 256, 256, 0, stream>>>(
        (const float4*)B, (float4*)A, NN * HIDC / 4);
    {
        long long tot = (long long)NE * (HIDC / 4);
        scatter_kernel<HIDC><<<(int)((tot + 255) / 256), 256, 0, stream>>>(ei, ew, B, A);
    }
    gemm_bias_kernel<HIDC, true><<<gemm_grid, 256, 0, stream>>>(A, W2, b2, B, NN);

    // ---- layer 3 (F=256) ----
    copy4_kernel<<<(NN * HIDC / 4 + 255) / 256, 256, 0, stream>>>(
        (const float4*)B, (float4*)A, NN * HIDC / 4);
    {
        long long tot = (long long)NE * (HIDC / 4);
        scatter_kernel<HIDC><<<(int)((tot + 255) / 256), 256, 0, stream>>>(ei, ew, B, A);
    }
    gemm_bias_kernel<HIDC, true><<<gemm_grid, 256, 0, stream>>>(A, W3, b3, B, NN);

    // ---- global mean pool + head ----
    {
        long long tot = (long long)NN * 64;
        pool_sum_kernel<<<(int)((tot + 255) / 256), 256, 0, stream>>>(B, batch, pooled, cnt);
    }
    head_kernel<<<NG, HIDC, 0, stream>>>(pooled, cnt, Wl, bl, (float*)d_out);
}

// Round 2
// 596.510 us; speedup vs baseline: 9.3837x; 9.3837x over previous
//
#include <hip/hip_runtime.h>

namespace {
constexpr int NN   = 10000;   // nodes
constexpr int NE   = 640000;  // edges
constexpr int INC  = 128;     // input channels
constexpr int HIDC = 256;     // hidden channels
constexpr int OUTC = 10;      // output channels
constexpr int NG   = 64;      // graphs
}

__global__ __launch_bounds__(256) void zero_f_kernel(float* __restrict__ p, int n) {
    int i = blockIdx.x * blockDim.x + threadIdx.x;
    if (i < n) p[i] = 0.0f;
}

__global__ __launch_bounds__(256) void zero_i_kernel(int* __restrict__ p, int n) {
    int i = blockIdx.x * blockDim.x + threadIdx.x;
    if (i < n) p[i] = 0;
}

// ---- CSR build: histogram by dst ----
__global__ __launch_bounds__(256) void hist_kernel(const int* __restrict__ ei,
                                                   int* __restrict__ deg) {
    int e = blockIdx.x * blockDim.x + threadIdx.x;
    if (e >= NE) return;
    atomicAdd(&deg[ei[NE + e]], 1);
}

// ---- single-block exclusive scan over deg[NN] -> row_start[NN+1], cur[NN] ----
__global__ __launch_bounds__(256) void scan_kernel(const int* __restrict__ deg,
                                                   int* __restrict__ row_start,
                                                   int* __restrict__ cur) {
    __shared__ int part[256];
    const int t = threadIdx.x;
    constexpr int C = (NN + 255) / 256;  // 40
    const int base = t * C;
    int sum = 0;
    for (int i = 0; i < C; i++) {
        int idx = base + i;
        if (idx < NN) sum += deg[idx];
    }
    part[t] = sum;
    __syncthreads();
    for (int off = 1; off < 256; off <<= 1) {
        int v = (t >= off) ? part[t - off] : 0;
        __syncthreads();
        part[t] += v;
        __syncthreads();
    }
    int run = (t == 0) ? 0 : part[t - 1];  // exclusive prefix of this chunk
    for (int i = 0; i < C; i++) {
        int idx = base + i;
        if (idx < NN) {
            row_start[idx] = run;
            cur[idx] = run;
            run += deg[idx];
        }
    }
    if (t == 255) row_start[NN] = run;  // == NE
}

// ---- bucket-scatter edges into CSR order ----
__global__ __launch_bounds__(256) void build_kernel(const int* __restrict__ ei,
                                                    const float* __restrict__ ew,
                                                    int* __restrict__ cur,
                                                    int* __restrict__ esrc,
                                                    float* __restrict__ ewd) {
    int e = blockIdx.x * blockDim.x + threadIdx.x;
    if (e >= NE) return;
    int d = ei[NE + e];
    int pos = atomicAdd(&cur[d], 1);
    esrc[pos] = ei[e];
    ewd[pos] = ew[e];
}

// ---- aggregation via CSR gather: one wave per node, lanes hold the row ----
// out[n] = x[n] + sum_e w_e * x[src_e]   (eps = 0)
template <int F>
__global__ __launch_bounds__(256) void gather_kernel(const int* __restrict__ row_start,
                                                     const int* __restrict__ esrc,
                                                     const float* __restrict__ ewd,
                                                     const float* __restrict__ x,
                                                     float* __restrict__ out) {
    constexpr int VEC = F / 64;  // floats per lane: 2 (F=128) or 4 (F=256)
    const int n = blockIdx.x * 4 + (threadIdx.x >> 6);
    const int lane = threadIdx.x & 63;
    if (n >= NN) return;
    const int beg = row_start[n];
    const int end = row_start[n + 1];

    float acc[VEC];
    {
        const float* r = x + (size_t)n * F + lane * VEC;
#pragma unroll
        for (int i = 0; i < VEC; i++) acc[i] = r[i];
    }
    int e = beg;
    // 2x unrolled: overlap the two gathers' latency
    for (; e + 1 < end; e += 2) {
        int s0 = esrc[e], s1 = esrc[e + 1];
        float w0 = ewd[e], w1 = ewd[e + 1];
        const float* r0 = x + (size_t)s0 * F + lane * VEC;
        const float* r1 = x + (size_t)s1 * F + lane * VEC;
        float v0[VEC], v1[VEC];
#pragma unroll
        for (int i = 0; i < VEC; i++) v0[i] = r0[i];
#pragma unroll
        for (int i = 0; i < VEC; i++) v1[i] = r1[i];
#pragma unroll
        for (int i = 0; i < VEC; i++) acc[i] += w0 * v0[i];
#pragma unroll
        for (int i = 0; i < VEC; i++) acc[i] += w1 * v1[i];
    }
    if (e < end) {
        int s0 = esrc[e];
        float w0 = ewd[e];
        const float* r0 = x + (size_t)s0 * F + lane * VEC;
#pragma unroll
        for (int i = 0; i < VEC; i++) acc[i] += w0 * r0[i];
    }
    float* o = out + (size_t)n * F + lane * VEC;
#pragma unroll
    for (int i = 0; i < VEC; i++) o[i] = acc[i];
}

// C[M,256] = relu(A[M,K] @ W[256,K]^T + bias). 64x64 tile, TK=16, 4x4 microtile.
template <int K, bool RELU>
__global__ __launch_bounds__(256) void gemm_bias_kernel(const float* __restrict__ A,
                                                        const float* __restrict__ W,
                                                        const float* __restrict__ bias,
                                                        float* __restrict__ C, int M) {
    constexpr int TM = 64, TN = 64, TK = 16;
    __shared__ float As[TK][TM + 1];
    __shared__ float Bs[TK][TN + 1];
    const int tid = threadIdx.x;
    const int tx = tid & 15;
    const int ty = tid >> 4;
    const int bm = blockIdx.x * TM;
    const int bn = blockIdx.y * TN;
    const int lrow = tid >> 2;
    const int lk4  = (tid & 3) * 4;

    float acc[4][4] = {};

    for (int k0 = 0; k0 < K; k0 += TK) {
        {
            int gm = bm + lrow;
            float4 v = make_float4(0.f, 0.f, 0.f, 0.f);
            if (gm < M) v = *(const float4*)(A + (size_t)gm * K + k0 + lk4);
            As[lk4 + 0][lrow] = v.x;
            As[lk4 + 1][lrow] = v.y;
            As[lk4 + 2][lrow] = v.z;
            As[lk4 + 3][lrow] = v.w;
        }
        {
            int gn = bn + lrow;
            float4 v = *(const float4*)(W + (size_t)gn * K + k0 + lk4);
            Bs[lk4 + 0][lrow] = v.x;
            Bs[lk4 + 1][lrow] = v.y;
            Bs[lk4 + 2][lrow] = v.z;
            Bs[lk4 + 3][lrow] = v.w;
        }
        __syncthreads();
#pragma unroll
        for (int kk = 0; kk < TK; kk++) {
            float a[4], b[4];
#pragma unroll
            for (int i = 0; i < 4; i++) a[i] = As[kk][ty * 4 + i];
#pragma unroll
            for (int j = 0; j < 4; j++) b[j] = Bs[kk][tx * 4 + j];
#pragma unroll
            for (int i = 0; i < 4; i++)
#pragma unroll
                for (int j = 0; j < 4; j++) acc[i][j] += a[i] * b[j];
        }
        __syncthreads();
    }

#pragma unroll
    for (int i = 0; i < 4; i++) {
        int m = bm + ty * 4 + i;
        if (m >= M) continue;
#pragma unroll
        for (int j = 0; j < 4; j++) {
            int n = bn + tx * 4 + j;
            float v = acc[i][j] + bias[n];
            if (RELU) v = fmaxf(v, 0.0f);
            C[(size_t)m * HIDC + n] = v;
        }
    }
}

__global__ __launch_bounds__(256) void pool_sum_kernel(const float* __restrict__ h,
                                                       const int* __restrict__ batch,
                                                       float* __restrict__ pooled,
                                                       float* __restrict__ cnt) {
    long long t = (long long)blockIdx.x * blockDim.x + threadIdx.x;
    int n = (int)(t >> 6);
    int c = (int)(t & 63);
    if (n >= NN) return;
    int g = batch[n];
    float4 v = ((const float4*)(h + (size_t)n * HIDC))[c];
    float* dp = pooled + (size_t)g * HIDC + c * 4;
    unsafeAtomicAdd(dp + 0, v.x);
    unsafeAtomicAdd(dp + 1, v.y);
    unsafeAtomicAdd(dp + 2, v.z);
    unsafeAtomicAdd(dp + 3, v.w);
    if (c == 0) unsafeAtomicAdd(&cnt[g], 1.0f);
}

__global__ __launch_bounds__(256) void head_kernel(const float* __restrict__ pooled,
                                                   const float* __restrict__ cnt,
                                                   const float* __restrict__ Wl,
                                                   const float* __restrict__ bl,
                                                   float* __restrict__ out) {
    __shared__ float s[HIDC];
    int g = blockIdx.x;
    float inv = 1.0f / fmaxf(cnt[g], 1.0f);
    s[threadIdx.x] = pooled[(size_t)g * HIDC + threadIdx.x] * inv;
    __syncthreads();
    if (threadIdx.x < OUTC) {
        int o = threadIdx.x;
        float acc = bl[o];
        for (int k = 0; k < HIDC; k++) acc += s[k] * Wl[(size_t)o * HIDC + k];
        out[(size_t)g * OUTC + o] = acc;
    }
}

extern "C" void kernel_launch(void* const* d_in, const int* in_sizes, int n_in,
                              void* d_out, int out_size, void* d_ws, size_t ws_size,
                              hipStream_t stream) {
    const float* x     = (const float*)d_in[0];
    const int*   ei    = (const int*)d_in[1];
    const int*   batch = (const int*)d_in[2];
    const float* ew    = (const float*)d_in[3];
    const float* W1    = (const float*)d_in[4];
    const float* b1    = (const float*)d_in[5];
    const float* W2    = (const float*)d_in[6];
    const float* b2    = (const float*)d_in[7];
    const float* W3    = (const float*)d_in[8];
    const float* b3    = (const float*)d_in[9];
    const float* Wl    = (const float*)d_in[10];
    const float* bl    = (const float*)d_in[11];

    // ---- workspace layout ----
    float* A      = (float*)d_ws;                    // [NN, 256]
    float* B      = A + (size_t)NN * HIDC;           // [NN, 256]
    float* pooled = B + (size_t)NN * HIDC;           // [NG, 256]
    float* cnt    = pooled + (size_t)NG * HIDC;      // [NG]
    float* ewd    = cnt + NG;                        // [NE] sorted edge weights
    int*   deg    = (int*)(ewd + NE);                // [NN]
    int*   row_start = deg + NN;                     // [NN+1]
    int*   cur    = row_start + NN + 1;              // [NN]
    int*   esrc   = cur + NN;                        // [NE] sorted edge sources

    // ---- CSR build (per call; no state carried across calls) ----
    zero_i_kernel<<<(NN + 255) / 256, 256, 0, stream>>>(deg, NN);
    zero_f_kernel<<<(NG * HIDC + NG + 255) / 256, 256, 0, stream>>>(pooled, NG * HIDC + NG);
    hist_kernel<<<(NE + 255) / 256, 256, 0, stream>>>(ei, deg);
    scan_kernel<<<1, 256, 0, stream>>>(deg, row_start, cur);
    build_kernel<<<(NE + 255) / 256, 256, 0, stream>>>(ei, ew, cur, esrc, ewd);

    dim3 gemm_grid((NN + 63) / 64, HIDC / 64);
    const int gather_grid = (NN + 3) / 4;

    // ---- layer 1 (F=128) ----
    gather_kernel<INC><<<gather_grid, 256, 0, stream>>>(row_start, esrc, ewd, x, A);
    gemm_bias_kernel<INC, true><<<gemm_grid, 256, 0, stream>>>(A, W1, b1, B, NN);

    // ---- layer 2 (F=256) ----
    gather_kernel<HIDC><<<gather_grid, 256, 0, stream>>>(row_start, esrc, ewd, B, A);
    gemm_bias_kernel<HIDC, true><<<gemm_grid, 256, 0, stream>>>(A, W2, b2, B, NN);

    // ---- layer 3 (F=256) ----
    gather_kernel<HIDC><<<gather_grid, 256, 0, stream>>>(row_start, esrc, ewd, B, A);
    gemm_bias_kernel<HIDC, true><<<gemm_grid, 256, 0, stream>>>(A, W3, b3, B, NN);

    // ---- global mean pool + head ----
    {
        long long tot = (long long)NN * 64;
        pool_sum_kernel<<<(int)((tot + 255) / 256), 256, 0, stream>>>(B, batch, pooled, cnt);
    }
    head_kernel<<<NG, HIDC, 0, stream>>>(pooled, cnt, Wl, bl, (float*)d_out);
}

// Round 3
// 502.739 us; speedup vs baseline: 11.1339x; 1.1865x over previous
//
#include <hip/hip_runtime.h>

namespace {
constexpr int NN   = 10000;   // nodes
constexpr int NE   = 640000;  // edges
constexpr int INC  = 128;     // input channels
constexpr int HIDC = 256;     // hidden channels
constexpr int OUTC = 10;      // output channels
constexpr int NG   = 64;      // graphs
constexpr int PP   = 8;       // pooling partials per graph
}

__global__ __launch_bounds__(256) void zero_i_kernel(int* __restrict__ p, int n) {
    int i = blockIdx.x * blockDim.x + threadIdx.x;
    if (i < n) p[i] = 0;
}

// ---- CSR build: histogram by dst ----
__global__ __launch_bounds__(256) void hist_kernel(const int* __restrict__ ei,
                                                   int* __restrict__ deg) {
    int e = blockIdx.x * blockDim.x + threadIdx.x;
    if (e >= NE) return;
    atomicAdd(&deg[ei[NE + e]], 1);
}

// ---- single-block exclusive scan over deg[NN] -> row_start[NN+1], cur[NN] ----
__global__ __launch_bounds__(256) void scan_kernel(const int* __restrict__ deg,
                                                   int* __restrict__ row_start,
                                                   int* __restrict__ cur) {
    __shared__ int part[256];
    const int t = threadIdx.x;
    constexpr int C = (NN + 255) / 256;  // 40
    const int base = t * C;
    int sum = 0;
    for (int i = 0; i < C; i++) {
        int idx = base + i;
        if (idx < NN) sum += deg[idx];
    }
    part[t] = sum;
    __syncthreads();
    for (int off = 1; off < 256; off <<= 1) {
        int v = (t >= off) ? part[t - off] : 0;
        __syncthreads();
        part[t] += v;
        __syncthreads();
    }
    int run = (t == 0) ? 0 : part[t - 1];
    for (int i = 0; i < C; i++) {
        int idx = base + i;
        if (idx < NN) {
            row_start[idx] = run;
            cur[idx] = run;
            run += deg[idx];
        }
    }
    if (t == 255) row_start[NN] = run;
}

// ---- bucket-scatter edges into CSR order ----
__global__ __launch_bounds__(256) void build_kernel(const int* __restrict__ ei,
                                                    const float* __restrict__ ew,
                                                    int* __restrict__ cur,
                                                    int* __restrict__ esrc,
                                                    float* __restrict__ ewd) {
    int e = blockIdx.x * blockDim.x + threadIdx.x;
    if (e >= NE) return;
    int d = ei[NE + e];
    int pos = atomicAdd(&cur[d], 1);
    esrc[pos] = ei[e];
    ewd[pos] = ew[e];
}

// ---- aggregation via CSR gather: one wave per node, lanes hold the row ----
template <int F>
__global__ __launch_bounds__(256) void gather_kernel(const int* __restrict__ row_start,
                                                     const int* __restrict__ esrc,
                                                     const float* __restrict__ ewd,
                                                     const float* __restrict__ x,
                                                     float* __restrict__ out) {
    constexpr int VEC = F / 64;
    const int n = blockIdx.x * 4 + (threadIdx.x >> 6);
    const int lane = threadIdx.x & 63;
    if (n >= NN) return;
    const int beg = row_start[n];
    const int end = row_start[n + 1];

    float acc[VEC];
    {
        const float* r = x + (size_t)n * F + lane * VEC;
#pragma unroll
        for (int i = 0; i < VEC; i++) acc[i] = r[i];
    }
    int e = beg;
    for (; e + 1 < end; e += 2) {
        int s0 = esrc[e], s1 = esrc[e + 1];
        float w0 = ewd[e], w1 = ewd[e + 1];
        const float* r0 = x + (size_t)s0 * F + lane * VEC;
        const float* r1 = x + (size_t)s1 * F + lane * VEC;
        float v0[VEC], v1[VEC];
#pragma unroll
        for (int i = 0; i < VEC; i++) v0[i] = r0[i];
#pragma unroll
        for (int i = 0; i < VEC; i++) v1[i] = r1[i];
#pragma unroll
        for (int i = 0; i < VEC; i++) acc[i] += w0 * v0[i];
#pragma unroll
        for (int i = 0; i < VEC; i++) acc[i] += w1 * v1[i];
    }
    if (e < end) {
        int s0 = esrc[e];
        float w0 = ewd[e];
        const float* r0 = x + (size_t)s0 * F + lane * VEC;
#pragma unroll
        for (int i = 0; i < VEC; i++) acc[i] += w0 * r0[i];
    }
    float* o = out + (size_t)n * F + lane * VEC;
#pragma unroll
    for (int i = 0; i < VEC; i++) o[i] = acc[i];
}

// C[M,256] = relu(A[M,K] @ W[256,K]^T + bias). 64x64 tile, TK=16, 4x4 microtile.
template <int K, bool RELU>
__global__ __launch_bounds__(256) void gemm_bias_kernel(const float* __restrict__ A,
                                                        const float* __restrict__ W,
                                                        const float* __restrict__ bias,
                                                        float* __restrict__ C, int M) {
    constexpr int TM = 64, TN = 64, TK = 16;
    __shared__ float As[TK][TM + 1];
    __shared__ float Bs[TK][TN + 1];
    const int tid = threadIdx.x;
    const int tx = tid & 15;
    const int ty = tid >> 4;
    const int bm = blockIdx.x * TM;
    const int bn = blockIdx.y * TN;
    const int lrow = tid >> 2;
    const int lk4  = (tid & 3) * 4;

    float acc[4][4] = {};

    for (int k0 = 0; k0 < K; k0 += TK) {
        {
            int gm = bm + lrow;
            float4 v = make_float4(0.f, 0.f, 0.f, 0.f);
            if (gm < M) v = *(const float4*)(A + (size_t)gm * K + k0 + lk4);
            As[lk4 + 0][lrow] = v.x;
            As[lk4 + 1][lrow] = v.y;
            As[lk4 + 2][lrow] = v.z;
            As[lk4 + 3][lrow] = v.w;
        }
        {
            int gn = bn + lrow;
            float4 v = *(const float4*)(W + (size_t)gn * K + k0 + lk4);
            Bs[lk4 + 0][lrow] = v.x;
            Bs[lk4 + 1][lrow] = v.y;
            Bs[lk4 + 2][lrow] = v.z;
            Bs[lk4 + 3][lrow] = v.w;
        }
        __syncthreads();
#pragma unroll
        for (int kk = 0; kk < TK; kk++) {
            float a[4], b[4];
#pragma unroll
            for (int i = 0; i < 4; i++) a[i] = As[kk][ty * 4 + i];
#pragma unroll
            for (int j = 0; j < 4; j++) b[j] = Bs[kk][tx * 4 + j];
#pragma unroll
            for (int i = 0; i < 4; i++)
#pragma unroll
                for (int j = 0; j < 4; j++) acc[i][j] += a[i] * b[j];
        }
        __syncthreads();
    }

#pragma unroll
    for (int i = 0; i < 4; i++) {
        int m = bm + ty * 4 + i;
        if (m >= M) continue;
#pragma unroll
        for (int j = 0; j < 4; j++) {
            int n = bn + tx * 4 + j;
            float v = acc[i][j] + bias[n];
            if (RELU) v = fmaxf(v, 0.0f);
            C[(size_t)m * HIDC + n] = v;
        }
    }
}

__device__ __forceinline__ int lower_bound_batch(const int* __restrict__ batch, int val) {
    int lo = 0, hi = NN;
    while (lo < hi) {
        int mid = (lo + hi) >> 1;
        if (batch[mid] < val) lo = mid + 1;
        else hi = mid;
    }
    return lo;
}

// ---- segmented mean-pool, stage 1: partial sums, no atomics ----
// grid (NG, PP); block 256 = one thread per channel.
__global__ __launch_bounds__(256) void pool_partial_kernel(const float* __restrict__ h,
                                                           const int* __restrict__ batch,
                                                           float* __restrict__ partials) {
    const int g = blockIdx.x;
    const int p = blockIdx.y;
    const int c = threadIdx.x;
    const int lo = lower_bound_batch(batch, g);
    const int hi = lower_bound_batch(batch, g + 1);
    const int cnt = hi - lo;
    const int chunk = (cnt + PP - 1) / PP;
    const int n0 = lo + p * chunk;
    const int n1 = min(hi, n0 + chunk);
    float sum = 0.0f;
    for (int n = n0; n < n1; n++) sum += h[(size_t)n * HIDC + c];
    partials[((size_t)g * PP + p) * HIDC + c] = sum;
}

// ---- stage 2: reduce partials, mean, apply head linear ----
__global__ __launch_bounds__(256) void head_kernel(const float* __restrict__ partials,
                                                   const int* __restrict__ batch,
                                                   const float* __restrict__ Wl,
                                                   const float* __restrict__ bl,
                                                   float* __restrict__ out) {
    __shared__ float s[HIDC];
    const int g = blockIdx.x;
    const int c = threadIdx.x;
    const int lo = lower_bound_batch(batch, g);
    const int hi = lower_bound_batch(batch, g + 1);
    const float inv = 1.0f / fmaxf((float)(hi - lo), 1.0f);
    float sum = 0.0f;
#pragma unroll
    for (int p = 0; p < PP; p++) sum += partials[((size_t)g * PP + p) * HIDC + c];
    s[c] = sum * inv;
    __syncthreads();
    if (c < OUTC) {
        float acc = bl[c];
        for (int k = 0; k < HIDC; k++) acc += s[k] * Wl[(size_t)c * HIDC + k];
        out[(size_t)g * OUTC + c] = acc;
    }
}

extern "C" void kernel_launch(void* const* d_in, const int* in_sizes, int n_in,
                              void* d_out, int out_size, void* d_ws, size_t ws_size,
                              hipStream_t stream) {
    const float* x     = (const float*)d_in[0];
    const int*   ei    = (const int*)d_in[1];
    const int*   batch = (const int*)d_in[2];
    const float* ew    = (const float*)d_in[3];
    const float* W1    = (const float*)d_in[4];
    const float* b1    = (const float*)d_in[5];
    const float* W2    = (const float*)d_in[6];
    const float* b2    = (const float*)d_in[7];
    const float* W3    = (const float*)d_in[8];
    const float* b3    = (const float*)d_in[9];
    const float* Wl    = (const float*)d_in[10];
    const float* bl    = (const float*)d_in[11];

    // ---- workspace layout ----
    float* A        = (float*)d_ws;                  // [NN, 256]
    float* B        = A + (size_t)NN * HIDC;         // [NN, 256]
    float* partials = B + (size_t)NN * HIDC;         // [NG, PP, 256]
    float* ewd      = partials + (size_t)NG * PP * HIDC;  // [NE]
    int*   deg      = (int*)(ewd + NE);              // [NN]
    int*   row_start = deg + NN;                     // [NN+1]
    int*   cur      = row_start + NN + 1;            // [NN]
    int*   esrc     = cur + NN;                      // [NE]

    // ---- CSR build (per call) ----
    zero_i_kernel<<<(NN + 255) / 256, 256, 0, stream>>>(deg, NN);
    hist_kernel<<<(NE + 255) / 256, 256, 0, stream>>>(ei, deg);
    scan_kernel<<<1, 256, 0, stream>>>(deg, row_start, cur);
    build_kernel<<<(NE + 255) / 256, 256, 0, stream>>>(ei, ew, cur, esrc, ewd);

    dim3 gemm_grid((NN + 63) / 64, HIDC / 64);
    const int gather_grid = (NN + 3) / 4;

    // ---- layer 1 (F=128) ----
    gather_kernel<INC><<<gather_grid, 256, 0, stream>>>(row_start, esrc, ewd, x, A);
    gemm_bias_kernel<INC, true><<<gemm_grid, 256, 0, stream>>>(A, W1, b1, B, NN);

    // ---- layer 2 (F=256) ----
    gather_kernel<HIDC><<<gather_grid, 256, 0, stream>>>(row_start, esrc, ewd, B, A);
    gemm_bias_kernel<HIDC, true><<<gemm_grid, 256, 0, stream>>>(A, W2, b2, B, NN);

    // ---- layer 3 (F=256) ----
    gather_kernel<HIDC><<<gather_grid, 256, 0, stream>>>(row_start, esrc, ewd, B, A);
    gemm_bias_kernel<HIDC, true><<<gemm_grid, 256, 0, stream>>>(A, W3, b3, B, NN);

    // ---- global mean pool (segmented, no atomics) + head ----
    pool_partial_kernel<<<dim3(NG, PP), 256, 0, stream>>>(B, batch, partials);
    head_kernel<<<NG, 256, 0, stream>>>(partials, batch, Wl, bl, (float*)d_out);
}

// Round 4
// 396.039 us; speedup vs baseline: 14.1336x; 1.2694x over previous
//
#include <hip/hip_runtime.h>

namespace {
constexpr int NN   = 10000;   // nodes
constexpr int NE   = 640000;  // edges
constexpr int INC  = 128;     // input channels
constexpr int HIDC = 256;     // hidden channels
constexpr int OUTC = 10;      // output channels
constexpr int NG   = 64;      // graphs
constexpr int PP   = 8;       // pooling partials per graph
}

typedef __attribute__((ext_vector_type(8))) short short8;
typedef __attribute__((ext_vector_type(4))) float f32x4;

__device__ __forceinline__ ushort f2bf(float f) {
    uint u = __float_as_uint(f);
    uint r = u + 0x7FFFu + ((u >> 16) & 1u);   // RNE
    return (ushort)(r >> 16);
}
__device__ __forceinline__ float bf2f(ushort u) {
    return __uint_as_float(((uint)u) << 16);
}

__global__ __launch_bounds__(256) void zero_i_kernel(int* __restrict__ p, int n) {
    int i = blockIdx.x * blockDim.x + threadIdx.x;
    if (i < n) p[i] = 0;
}

// fp32 -> bf16, 4 elements/thread
__global__ __launch_bounds__(256) void f2bf_kernel(const float* __restrict__ in,
                                                   ushort* __restrict__ out, int n4) {
    int i = blockIdx.x * blockDim.x + threadIdx.x;
    if (i >= n4) return;
    float4 v = ((const float4*)in)[i];
    ushort4 o;
    o.x = f2bf(v.x); o.y = f2bf(v.y); o.z = f2bf(v.z); o.w = f2bf(v.w);
    ((ushort4*)out)[i] = o;
}

// ---- CSR build: histogram by dst ----
__global__ __launch_bounds__(256) void hist_kernel(const int* __restrict__ ei,
                                                   int* __restrict__ deg) {
    int e = blockIdx.x * blockDim.x + threadIdx.x;
    if (e >= NE) return;
    atomicAdd(&deg[ei[NE + e]], 1);
}

// ---- single-block exclusive scan over deg[NN] -> row_start[NN+1], cur[NN] ----
__global__ __launch_bounds__(256) void scan_kernel(const int* __restrict__ deg,
                                                   int* __restrict__ row_start,
                                                   int* __restrict__ cur) {
    __shared__ int part[256];
    const int t = threadIdx.x;
    constexpr int C = (NN + 255) / 256;  // 40
    const int base = t * C;
    int sum = 0;
    for (int i = 0; i < C; i++) {
        int idx = base + i;
        if (idx < NN) sum += deg[idx];
    }
    part[t] = sum;
    __syncthreads();
    for (int off = 1; off < 256; off <<= 1) {
        int v = (t >= off) ? part[t - off] : 0;
        __syncthreads();
        part[t] += v;
        __syncthreads();
    }
    int run = (t == 0) ? 0 : part[t - 1];
    for (int i = 0; i < C; i++) {
        int idx = base + i;
        if (idx < NN) {
            row_start[idx] = run;
            cur[idx] = run;
            run += deg[idx];
        }
    }
    if (t == 255) row_start[NN] = run;
}

// ---- bucket-scatter edges into CSR order ----
__global__ __launch_bounds__(256) void build_kernel(const int* __restrict__ ei,
                                                    const float* __restrict__ ew,
                                                    int* __restrict__ cur,
                                                    int* __restrict__ esrc,
                                                    float* __restrict__ ewd) {
    int e = blockIdx.x * blockDim.x + threadIdx.x;
    if (e >= NE) return;
    int d = ei[NE + e];
    int pos = atomicAdd(&cur[d], 1);
    esrc[pos] = ei[e];
    ewd[pos] = ew[e];
}

// ---- aggregation via CSR gather (bf16 in/out, fp32 accumulate) ----
// out[n] = x[n] + sum_e w_e * x[src_e]
template <int F>
__global__ __launch_bounds__(256) void gather_bf16_kernel(const int* __restrict__ row_start,
                                                          const int* __restrict__ esrc,
                                                          const float* __restrict__ ewd,
                                                          const ushort* __restrict__ x,
                                                          ushort* __restrict__ out) {
    constexpr int VEC = F / 64;  // bf16 per lane: 2 (F=128) or 4 (F=256)
    const int n = blockIdx.x * 4 + (threadIdx.x >> 6);
    const int lane = threadIdx.x & 63;
    if (n >= NN) return;
    const int beg = row_start[n];
    const int end = row_start[n + 1];

    float acc[VEC];
    {
        ushort v[VEC];
        if (VEC == 4) *(ushort4*)v = *(const ushort4*)(x + (size_t)n * F + lane * VEC);
        else          *(ushort2*)v = *(const ushort2*)(x + (size_t)n * F + lane * VEC);
#pragma unroll
        for (int i = 0; i < VEC; i++) acc[i] = bf2f(v[i]);
    }
    int e = beg;
    for (; e + 1 < end; e += 2) {
        int s0 = esrc[e], s1 = esrc[e + 1];
        float w0 = ewd[e], w1 = ewd[e + 1];
        ushort v0[VEC], v1[VEC];
        if (VEC == 4) {
            *(ushort4*)v0 = *(const ushort4*)(x + (size_t)s0 * F + lane * VEC);
            *(ushort4*)v1 = *(const ushort4*)(x + (size_t)s1 * F + lane * VEC);
        } else {
            *(ushort2*)v0 = *(const ushort2*)(x + (size_t)s0 * F + lane * VEC);
            *(ushort2*)v1 = *(const ushort2*)(x + (size_t)s1 * F + lane * VEC);
        }
#pragma unroll
        for (int i = 0; i < VEC; i++) acc[i] += w0 * bf2f(v0[i]);
#pragma unroll
        for (int i = 0; i < VEC; i++) acc[i] += w1 * bf2f(v1[i]);
    }
    if (e < end) {
        int s0 = esrc[e];
        float w0 = ewd[e];
        ushort v0[VEC];
        if (VEC == 4) *(ushort4*)v0 = *(const ushort4*)(x + (size_t)s0 * F + lane * VEC);
        else          *(ushort2*)v0 = *(const ushort2*)(x + (size_t)s0 * F + lane * VEC);
#pragma unroll
        for (int i = 0; i < VEC; i++) acc[i] += w0 * bf2f(v0[i]);
    }
    ushort o[VEC];
#pragma unroll
    for (int i = 0; i < VEC; i++) o[i] = f2bf(acc[i]);
    if (VEC == 4) *(ushort4*)(out + (size_t)n * F + lane * VEC) = *(ushort4*)o;
    else          *(ushort2*)(out + (size_t)n * F + lane * VEC) = *(ushort2*)o;
}

// ---- MFMA bf16 GEMM: C[M,256] = relu(A[M,K] @ W[256,K]^T + bias), bf16 out ----
// Block: 256 thr = 4 waves. Tile 128(M) x 64(N). Full W slab (64 rows x K) in LDS,
// A fragments streamed from global. One barrier total.
// mfma_f32_16x16x32_bf16 layouts (learn_hip verified):
//   A: lane holds A[m=lane&15][k=(lane>>4)*8+j], j=0..7  (16B contiguous)
//   B: lane holds B[k=(lane>>4)*8+j][n=lane&15]  == W[n][k...k+7] (16B contiguous)
//   C/D: col=lane&15, row=(lane>>4)*4+reg
template <int K>
__global__ __launch_bounds__(256) void mfma_gemm_kernel(const ushort* __restrict__ A,
                                                        const ushort* __restrict__ Wb,
                                                        const float* __restrict__ bias,
                                                        ushort* __restrict__ C, int M) {
    constexpr int LDW = K + 8;  // +16B pad: row stride 528B/272B -> 4-bank skew, 2-way free
    __shared__ ushort Ws[64 * LDW];
    const int tid = threadIdx.x;
    const int bm = blockIdx.x * 128;
    const int bn = blockIdx.y * 64;

    // stage W rows [bn, bn+64) into LDS (16B chunks)
    constexpr int CPR = K / 8;
    for (int idx = tid; idx < 64 * CPR; idx += 256) {
        int r = idx / CPR, c = idx % CPR;
        uint4 v = *(const uint4*)(Wb + (size_t)(bn + r) * K + c * 8);
        *(uint4*)(&Ws[r * LDW + c * 8]) = v;
    }
    __syncthreads();

    const int wave = tid >> 6;
    const int lane = tid & 63;
    const int lrow = lane & 15;
    const int lq   = lane >> 4;
    const int m0 = bm + wave * 32;

    f32x4 acc[2][4] = {};
    const int r0 = min(m0 + lrow, M - 1);        // clamp: edge block reads row M-1
    const int r1 = min(m0 + 16 + lrow, M - 1);

    for (int k0 = 0; k0 < K; k0 += 32) {
        const int kk = k0 + lq * 8;
        short8 a0 = *(const short8*)(A + (size_t)r0 * K + kk);
        short8 a1 = *(const short8*)(A + (size_t)r1 * K + kk);
        short8 b[4];
#pragma unroll
        for (int j = 0; j < 4; j++)
            b[j] = *(const short8*)(&Ws[(j * 16 + lrow) * LDW + kk]);
#pragma unroll
        for (int j = 0; j < 4; j++) {
            acc[0][j] = __builtin_amdgcn_mfma_f32_16x16x32_bf16(a0, b[j], acc[0][j], 0, 0, 0);
            acc[1][j] = __builtin_amdgcn_mfma_f32_16x16x32_bf16(a1, b[j], acc[1][j], 0, 0, 0);
        }
    }

#pragma unroll
    for (int sub = 0; sub < 2; sub++) {
#pragma unroll
        for (int j = 0; j < 4; j++) {
            const int gn = bn + j * 16 + lrow;
            const float bv = bias[gn];
#pragma unroll
            for (int i = 0; i < 4; i++) {
                const int gm = m0 + sub * 16 + lq * 4 + i;
                if (gm < M) {
                    float v = acc[sub][j][i] + bv;
                    v = fmaxf(v, 0.0f);
                    C[(size_t)gm * HIDC + gn] = f2bf(v);
                }
            }
        }
    }
}

__device__ __forceinline__ int lower_bound_batch(const int* __restrict__ batch, int val) {
    int lo = 0, hi = NN;
    while (lo < hi) {
        int mid = (lo + hi) >> 1;
        if (batch[mid] < val) lo = mid + 1;
        else hi = mid;
    }
    return lo;
}

// ---- segmented mean-pool stage 1: partial sums over bf16 h ----
__global__ __launch_bounds__(256) void pool_partial_kernel(const ushort* __restrict__ h,
                                                           const int* __restrict__ batch,
                                                           float* __restrict__ partials) {
    const int g = blockIdx.x;
    const int p = blockIdx.y;
    const int c = threadIdx.x;
    const int lo = lower_bound_batch(batch, g);
    const int hi = lower_bound_batch(batch, g + 1);
    const int cnt = hi - lo;
    const int chunk = (cnt + PP - 1) / PP;
    const int n0 = lo + p * chunk;
    const int n1 = min(hi, n0 + chunk);
    float sum = 0.0f;
    for (int n = n0; n < n1; n++) sum += bf2f(h[(size_t)n * HIDC + c]);
    partials[((size_t)g * PP + p) * HIDC + c] = sum;
}

// ---- stage 2: reduce partials, mean, head linear (fp32) ----
__global__ __launch_bounds__(256) void head_kernel(const float* __restrict__ partials,
                                                   const int* __restrict__ batch,
                                                   const float* __restrict__ Wl,
                                                   const float* __restrict__ bl,
                                                   float* __restrict__ out) {
    __shared__ float s[HIDC];
    const int g = blockIdx.x;
    const int c = threadIdx.x;
    const int lo = lower_bound_batch(batch, g);
    const int hi = lower_bound_batch(batch, g + 1);
    const float inv = 1.0f / fmaxf((float)(hi - lo), 1.0f);
    float sum = 0.0f;
#pragma unroll
    for (int p = 0; p < PP; p++) sum += partials[((size_t)g * PP + p) * HIDC + c];
    s[c] = sum * inv;
    __syncthreads();
    if (c < OUTC) {
        float acc = bl[c];
        for (int k = 0; k < HIDC; k++) acc += s[k] * Wl[(size_t)c * HIDC + k];
        out[(size_t)g * OUTC + c] = acc;
    }
}

extern "C" void kernel_launch(void* const* d_in, const int* in_sizes, int n_in,
                              void* d_out, int out_size, void* d_ws, size_t ws_size,
                              hipStream_t stream) {
    const float* x     = (const float*)d_in[0];
    const int*   ei    = (const int*)d_in[1];
    const int*   batch = (const int*)d_in[2];
    const float* ew    = (const float*)d_in[3];
    const float* W1    = (const float*)d_in[4];
    const float* b1    = (const float*)d_in[5];
    const float* W2    = (const float*)d_in[6];
    const float* b2    = (const float*)d_in[7];
    const float* W3    = (const float*)d_in[8];
    const float* b3    = (const float*)d_in[9];
    const float* Wl    = (const float*)d_in[10];
    const float* bl    = (const float*)d_in[11];

    // ---- workspace layout (16B-aligned regions) ----
    char* p = (char*)d_ws;
    ushort* xb     = (ushort*)p; p += (size_t)NN * INC * 2;      // x in bf16
    ushort* agg128 = (ushort*)p; p += (size_t)NN * INC * 2;      // layer-1 aggregation
    ushort* agg256 = (ushort*)p; p += (size_t)NN * HIDC * 2;     // layer-2/3 aggregation
    ushort* h      = (ushort*)p; p += (size_t)NN * HIDC * 2;     // activations
    ushort* w1b    = (ushort*)p; p += (size_t)HIDC * INC * 2;
    ushort* w2b    = (ushort*)p; p += (size_t)HIDC * HIDC * 2;
    ushort* w3b    = (ushort*)p; p += (size_t)HIDC * HIDC * 2;
    float*  partials = (float*)p; p += (size_t)NG * PP * HIDC * 4;
    float*  ewd    = (float*)p;  p += (size_t)NE * 4;
    int*    deg    = (int*)p;    p += (size_t)NN * 4;
    int*    row_start = (int*)p; p += 40016;                     // NN+1 ints, padded
    int*    cur    = (int*)p;    p += (size_t)NN * 4;
    int*    esrc   = (int*)p;    p += (size_t)NE * 4;

    // ---- CSR build (per call) ----
    zero_i_kernel<<<(NN + 255) / 256, 256, 0, stream>>>(deg, NN);
    hist_kernel<<<(NE + 255) / 256, 256, 0, stream>>>(ei, deg);
    scan_kernel<<<1, 256, 0, stream>>>(deg, row_start, cur);
    build_kernel<<<(NE + 255) / 256, 256, 0, stream>>>(ei, ew, cur, esrc, ewd);

    // ---- bf16 conversions ----
    f2bf_kernel<<<(NN * INC / 4 + 255) / 256, 256, 0, stream>>>(x, xb, NN * INC / 4);
    f2bf_kernel<<<(HIDC * INC / 4 + 255) / 256, 256, 0, stream>>>(W1, w1b, HIDC * INC / 4);
    f2bf_kernel<<<(HIDC * HIDC / 4 + 255) / 256, 256, 0, stream>>>(W2, w2b, HIDC * HIDC / 4);
    f2bf_kernel<<<(HIDC * HIDC / 4 + 255) / 256, 256, 0, stream>>>(W3, w3b, HIDC * HIDC / 4);

    const int gather_grid = (NN + 3) / 4;
    dim3 gemm_grid((NN + 127) / 128, HIDC / 64);

    // ---- layer 1 (K=128) ----
    gather_bf16_kernel<INC><<<gather_grid, 256, 0, stream>>>(row_start, esrc, ewd, xb, agg128);
    mfma_gemm_kernel<INC><<<gemm_grid, 256, 0, stream>>>(agg128, w1b, b1, h, NN);

    // ---- layer 2 (K=256) ----
    gather_bf16_kernel<HIDC><<<gather_grid, 256, 0, stream>>>(row_start, esrc, ewd, h, agg256);
    mfma_gemm_kernel<HIDC><<<gemm_grid, 256, 0, stream>>>(agg256, w2b, b2, h, NN);

    // ---- layer 3 (K=256) ----
    gather_bf16_kernel<HIDC><<<gather_grid, 256, 0, stream>>>(row_start, esrc, ewd, h, agg256);
    mfma_gemm_kernel<HIDC><<<gemm_grid, 256, 0, stream>>>(agg256, w3b, b3, h, NN);

    // ---- global mean pool + head ----
    pool_partial_kernel<<<dim3(NG, PP), 256, 0, stream>>>(h, batch, partials);
    head_kernel<<<NG, 256, 0, stream>>>(partials, batch, Wl, bl, (float*)d_out);
}

// Round 5
// 385.892 us; speedup vs baseline: 14.5052x; 1.0263x over previous
//
#include <hip/hip_runtime.h>

namespace {
constexpr int NN   = 10000;   // nodes
constexpr int NE   = 640000;  // edges
constexpr int INC  = 128;     // input channels
constexpr int HIDC = 256;     // hidden channels
constexpr int OUTC = 10;      // output channels
constexpr int NG   = 64;      // graphs
constexpr int PP   = 8;       // pooling partials per graph
}

typedef __attribute__((ext_vector_type(8))) short short8;
typedef __attribute__((ext_vector_type(4))) float f32x4;

__device__ __forceinline__ ushort f2bf(float f) {
    uint u = __float_as_uint(f);
    uint r = u + 0x7FFFu + ((u >> 16) & 1u);   // RNE
    return (ushort)(r >> 16);
}
__device__ __forceinline__ float bf2f(ushort u) {
    return __uint_as_float(((uint)u) << 16);
}

__global__ __launch_bounds__(256) void zero_i_kernel(int* __restrict__ p, int n) {
    int i = blockIdx.x * blockDim.x + threadIdx.x;
    if (i < n) p[i] = 0;
}

// fp32 -> bf16, 4 elements/thread (for x only; weights fused into GEMM staging)
__global__ __launch_bounds__(256) void f2bf_kernel(const float* __restrict__ in,
                                                   ushort* __restrict__ out, int n4) {
    int i = blockIdx.x * blockDim.x + threadIdx.x;
    if (i >= n4) return;
    float4 v = ((const float4*)in)[i];
    ushort4 o;
    o.x = f2bf(v.x); o.y = f2bf(v.y); o.z = f2bf(v.z); o.w = f2bf(v.w);
    ((ushort4*)out)[i] = o;
}

// ---- CSR build: histogram by dst ----
__global__ __launch_bounds__(256) void hist_kernel(const int* __restrict__ ei,
                                                   int* __restrict__ deg) {
    int e = blockIdx.x * blockDim.x + threadIdx.x;
    if (e >= NE) return;
    atomicAdd(&deg[ei[NE + e]], 1);
}

// ---- single-block exclusive scan over deg[NN] -> row_start[NN+1], cur[NN] ----
__global__ __launch_bounds__(1024) void scan_kernel(const int* __restrict__ deg,
                                                    int* __restrict__ row_start,
                                                    int* __restrict__ cur) {
    __shared__ int part[1024];
    const int t = threadIdx.x;
    constexpr int C = (NN + 1023) / 1024;  // 10
    const int base = t * C;
    int sum = 0;
#pragma unroll
    for (int i = 0; i < C; i++) {
        int idx = base + i;
        if (idx < NN) sum += deg[idx];
    }
    part[t] = sum;
    __syncthreads();
    for (int off = 1; off < 1024; off <<= 1) {
        int v = (t >= off) ? part[t - off] : 0;
        __syncthreads();
        part[t] += v;
        __syncthreads();
    }
    int run = (t == 0) ? 0 : part[t - 1];
#pragma unroll
    for (int i = 0; i < C; i++) {
        int idx = base + i;
        if (idx < NN) {
            row_start[idx] = run;
            cur[idx] = run;
            run += deg[idx];
        }
    }
    if (t == 1023) row_start[NN] = run;
}

// ---- bucket-scatter edges into CSR order: one 8B record per edge ----
__global__ __launch_bounds__(256) void build_kernel(const int* __restrict__ ei,
                                                    const float* __restrict__ ew,
                                                    int* __restrict__ cur,
                                                    int2* __restrict__ erec) {
    int e = blockIdx.x * blockDim.x + threadIdx.x;
    if (e >= NE) return;
    int d = ei[NE + e];
    int pos = atomicAdd(&cur[d], 1);
    erec[pos] = make_int2(ei[e], __float_as_int(ew[e]));
}

// ---- aggregation via CSR gather (bf16 in/out, fp32 accumulate) ----
// out[n] = x[n] + sum_e w_e * x[src_e]
template <int F>
__global__ __launch_bounds__(256) void gather_bf16_kernel(const int* __restrict__ row_start,
                                                          const int2* __restrict__ erec,
                                                          const ushort* __restrict__ x,
                                                          ushort* __restrict__ out) {
    constexpr int VEC = F / 64;  // bf16 per lane: 2 (F=128) or 4 (F=256)
    const int n = blockIdx.x * 4 + (threadIdx.x >> 6);
    const int lane = threadIdx.x & 63;
    if (n >= NN) return;
    const int beg = row_start[n];
    const int end = row_start[n + 1];

    float acc[VEC];
    {
        ushort v[VEC];
        if (VEC == 4) *(ushort4*)v = *(const ushort4*)(x + (size_t)n * F + lane * VEC);
        else          *(ushort2*)v = *(const ushort2*)(x + (size_t)n * F + lane * VEC);
#pragma unroll
        for (int i = 0; i < VEC; i++) acc[i] = bf2f(v[i]);
    }
    int e = beg;
    for (; e + 1 < end; e += 2) {
        int2 rec0 = erec[e], rec1 = erec[e + 1];
        float w0 = __int_as_float(rec0.y), w1 = __int_as_float(rec1.y);
        ushort v0[VEC], v1[VEC];
        if (VEC == 4) {
            *(ushort4*)v0 = *(const ushort4*)(x + (size_t)rec0.x * F + lane * VEC);
            *(ushort4*)v1 = *(const ushort4*)(x + (size_t)rec1.x * F + lane * VEC);
        } else {
            *(ushort2*)v0 = *(const ushort2*)(x + (size_t)rec0.x * F + lane * VEC);
            *(ushort2*)v1 = *(const ushort2*)(x + (size_t)rec1.x * F + lane * VEC);
        }
#pragma unroll
        for (int i = 0; i < VEC; i++) acc[i] += w0 * bf2f(v0[i]);
#pragma unroll
        for (int i = 0; i < VEC; i++) acc[i] += w1 * bf2f(v1[i]);
    }
    if (e < end) {
        int2 rec0 = erec[e];
        float w0 = __int_as_float(rec0.y);
        ushort v0[VEC];
        if (VEC == 4) *(ushort4*)v0 = *(const ushort4*)(x + (size_t)rec0.x * F + lane * VEC);
        else          *(ushort2*)v0 = *(const ushort2*)(x + (size_t)rec0.x * F + lane * VEC);
#pragma unroll
        for (int i = 0; i < VEC; i++) acc[i] += w0 * bf2f(v0[i]);
    }
    ushort o[VEC];
#pragma unroll
    for (int i = 0; i < VEC; i++) o[i] = f2bf(acc[i]);
    if (VEC == 4) *(ushort4*)(out + (size_t)n * F + lane * VEC) = *(ushort4*)o;
    else          *(ushort2*)(out + (size_t)n * F + lane * VEC) = *(ushort2*)o;
}

// ---- MFMA bf16 GEMM: C[M,256] = relu(A[M,K] @ W[256,K]^T + bias), bf16 out ----
// W is fp32 in global; converted to bf16 during LDS staging.
// Block: 256 thr = 4 waves. Tile 128(M) x 64(N). One barrier total.
template <int K>
__global__ __launch_bounds__(256) void mfma_gemm_kernel(const ushort* __restrict__ A,
                                                        const float* __restrict__ W,
                                                        const float* __restrict__ bias,
                                                        ushort* __restrict__ C, int M) {
    constexpr int LDW = K + 8;  // pad: row stride 528B/272B -> bank skew
    __shared__ ushort Ws[64 * LDW];
    const int tid = threadIdx.x;
    const int bm = blockIdx.x * 128;
    const int bn = blockIdx.y * 64;

    // stage W rows [bn, bn+64) into LDS, fp32 -> bf16 (4 values per chunk)
    constexpr int CPR = K / 4;
    for (int idx = tid; idx < 64 * CPR; idx += 256) {
        int r = idx / CPR, c = idx % CPR;
        float4 v = *(const float4*)(W + (size_t)(bn + r) * K + c * 4);
        ushort4 o;
        o.x = f2bf(v.x); o.y = f2bf(v.y); o.z = f2bf(v.z); o.w = f2bf(v.w);
        *(ushort4*)(&Ws[r * LDW + c * 4]) = o;
    }
    __syncthreads();

    const int wave = tid >> 6;
    const int lane = tid & 63;
    const int lrow = lane & 15;
    const int lq   = lane >> 4;
    const int m0 = bm + wave * 32;

    f32x4 acc[2][4] = {};
    const int r0 = min(m0 + lrow, M - 1);
    const int r1 = min(m0 + 16 + lrow, M - 1);

    for (int k0 = 0; k0 < K; k0 += 32) {
        const int kk = k0 + lq * 8;
        short8 a0 = *(const short8*)(A + (size_t)r0 * K + kk);
        short8 a1 = *(const short8*)(A + (size_t)r1 * K + kk);
        short8 b[4];
#pragma unroll
        for (int j = 0; j < 4; j++)
            b[j] = *(const short8*)(&Ws[(j * 16 + lrow) * LDW + kk]);
#pragma unroll
        for (int j = 0; j < 4; j++) {
            acc[0][j] = __builtin_amdgcn_mfma_f32_16x16x32_bf16(a0, b[j], acc[0][j], 0, 0, 0);
            acc[1][j] = __builtin_amdgcn_mfma_f32_16x16x32_bf16(a1, b[j], acc[1][j], 0, 0, 0);
        }
    }

#pragma unroll
    for (int sub = 0; sub < 2; sub++) {
#pragma unroll
        for (int j = 0; j < 4; j++) {
            const int gn = bn + j * 16 + lrow;
            const float bv = bias[gn];
#pragma unroll
            for (int i = 0; i < 4; i++) {
                const int gm = m0 + sub * 16 + lq * 4 + i;
                if (gm < M) {
                    float v = acc[sub][j][i] + bv;
                    v = fmaxf(v, 0.0f);
                    C[(size_t)gm * HIDC + gn] = f2bf(v);
                }
            }
        }
    }
}

__device__ __forceinline__ int lower_bound_batch(const int* __restrict__ batch, int val) {
    int lo = 0, hi = NN;
    while (lo < hi) {
        int mid = (lo + hi) >> 1;
        if (batch[mid] < val) lo = mid + 1;
        else hi = mid;
    }
    return lo;
}

// ---- segmented mean-pool stage 1: partial sums over bf16 h ----
__global__ __launch_bounds__(256) void pool_partial_kernel(const ushort* __restrict__ h,
                                                           const int* __restrict__ batch,
                                                           float* __restrict__ partials) {
    const int g = blockIdx.x;
    const int p = blockIdx.y;
    const int c = threadIdx.x;
    const int lo = lower_bound_batch(batch, g);
    const int hi = lower_bound_batch(batch, g + 1);
    const int cnt = hi - lo;
    const int chunk = (cnt + PP - 1) / PP;
    const int n0 = lo + p * chunk;
    const int n1 = min(hi, n0 + chunk);
    float sum = 0.0f;
    for (int n = n0; n < n1; n++) sum += bf2f(h[(size_t)n * HIDC + c]);
    partials[((size_t)g * PP + p) * HIDC + c] = sum;
}

// ---- stage 2: reduce partials, mean, head linear (fp32) ----
__global__ __launch_bounds__(256) void head_kernel(const float* __restrict__ partials,
                                                   const int* __restrict__ batch,
                                                   const float* __restrict__ Wl,
                                                   const float* __restrict__ bl,
                                                   float* __restrict__ out) {
    __shared__ float s[HIDC];
    const int g = blockIdx.x;
    const int c = threadIdx.x;
    const int lo = lower_bound_batch(batch, g);
    const int hi = lower_bound_batch(batch, g + 1);
    const float inv = 1.0f / fmaxf((float)(hi - lo), 1.0f);
    float sum = 0.0f;
#pragma unroll
    for (int p = 0; p < PP; p++) sum += partials[((size_t)g * PP + p) * HIDC + c];
    s[c] = sum * inv;
    __syncthreads();
    if (c < OUTC) {
        float acc = bl[c];
        for (int k = 0; k < HIDC; k++) acc += s[k] * Wl[(size_t)c * HIDC + k];
        out[(size_t)g * OUTC + c] = acc;
    }
}

extern "C" void kernel_launch(void* const* d_in, const int* in_sizes, int n_in,
                              void* d_out, int out_size, void* d_ws, size_t ws_size,
                              hipStream_t stream) {
    const float* x     = (const float*)d_in[0];
    const int*   ei    = (const int*)d_in[1];
    const int*   batch = (const int*)d_in[2];
    const float* ew    = (const float*)d_in[3];
    const float* W1    = (const float*)d_in[4];
    const float* b1    = (const float*)d_in[5];
    const float* W2    = (const float*)d_in[6];
    const float* b2    = (const float*)d_in[7];
    const float* W3    = (const float*)d_in[8];
    const float* b3    = (const float*)d_in[9];
    const float* Wl    = (const float*)d_in[10];
    const float* bl    = (const float*)d_in[11];

    // ---- workspace layout (8/16B-aligned regions) ----
    char* p = (char*)d_ws;
    ushort* xb     = (ushort*)p; p += (size_t)NN * INC * 2;       // x in bf16
    ushort* agg128 = (ushort*)p; p += (size_t)NN * INC * 2;       // layer-1 aggregation
    ushort* agg256 = (ushort*)p; p += (size_t)NN * HIDC * 2;      // layer-2/3 aggregation
    ushort* h      = (ushort*)p; p += (size_t)NN * HIDC * 2;      // activations
    int2*   erec   = (int2*)p;   p += (size_t)NE * 8;             // CSR records {src, w}
    float*  partials = (float*)p; p += (size_t)NG * PP * HIDC * 4;
    int*    deg    = (int*)p;    p += (size_t)NN * 4;
    int*    row_start = (int*)p; p += 40016;                      // NN+1 ints, padded
    int*    cur    = (int*)p;    p += (size_t)NN * 4;

    // ---- CSR build (per call) ----
    zero_i_kernel<<<(NN + 255) / 256, 256, 0, stream>>>(deg, NN);
    hist_kernel<<<(NE + 255) / 256, 256, 0, stream>>>(ei, deg);
    scan_kernel<<<1, 1024, 0, stream>>>(deg, row_start, cur);
    build_kernel<<<(NE + 255) / 256, 256, 0, stream>>>(ei, ew, cur, erec);

    // ---- x -> bf16 ----
    f2bf_kernel<<<(NN * INC / 4 + 255) / 256, 256, 0, stream>>>(x, xb, NN * INC / 4);

    const int gather_grid = (NN + 3) / 4;
    dim3 gemm_grid((NN + 127) / 128, HIDC / 64);

    // ---- layer 1 (K=128) ----
    gather_bf16_kernel<INC><<<gather_grid, 256, 0, stream>>>(row_start, erec, xb, agg128);
    mfma_gemm_kernel<INC><<<gemm_grid, 256, 0, stream>>>(agg128, W1, b1, h, NN);

    // ---- layer 2 (K=256) ----
    gather_bf16_kernel<HIDC><<<gather_grid, 256, 0, stream>>>(row_start, erec, h, agg256);
    mfma_gemm_kernel<HIDC><<<gemm_grid, 256, 0, stream>>>(agg256, W2, b2, h, NN);

    // ---- layer 3 (K=256) ----
    gather_bf16_kernel<HIDC><<<gather_grid, 256, 0, stream>>>(row_start, erec, h, agg256);
    mfma_gemm_kernel<HIDC><<<gemm_grid, 256, 0, stream>>>(agg256, W3, b3, h, NN);

    // ---- global mean pool + head ----
    pool_partial_kernel<<<dim3(NG, PP), 256, 0, stream>>>(h, batch, partials);
    head_kernel<<<NG, 256, 0, stream>>>(partials, batch, Wl, bl, (float*)d_out);
}

// Round 6
// 332.774 us; speedup vs baseline: 16.8206x; 1.1596x over previous
//
#include <hip/hip_runtime.h>

namespace {
constexpr int NN   = 10000;   // nodes
constexpr int NE   = 640000;  // edges
constexpr int INC  = 128;     // input channels
constexpr int HIDC = 256;     // hidden channels
constexpr int OUTC = 10;      // output channels
constexpr int NG   = 64;      // graphs
constexpr int PP   = 8;       // pooling partials per graph
}

typedef __attribute__((ext_vector_type(8))) short short8;
typedef __attribute__((ext_vector_type(4))) float f32x4;

__device__ __forceinline__ ushort f2bf(float f) {
    uint u = __float_as_uint(f);
    uint r = u + 0x7FFFu + ((u >> 16) & 1u);   // RNE
    return (ushort)(r >> 16);
}
__device__ __forceinline__ float bf2f(ushort u) {
    return __uint_as_float(((uint)u) << 16);
}

__global__ __launch_bounds__(256) void zero_i_kernel(int* __restrict__ p, int n) {
    int i = blockIdx.x * blockDim.x + threadIdx.x;
    if (i < n) p[i] = 0;
}

// fp32 -> bf16, 4 elements/thread (x only; weights converted in GEMM staging)
__global__ __launch_bounds__(256) void f2bf_kernel(const float* __restrict__ in,
                                                   ushort* __restrict__ out, int n4) {
    int i = blockIdx.x * blockDim.x + threadIdx.x;
    if (i >= n4) return;
    float4 v = ((const float4*)in)[i];
    ushort4 o;
    o.x = f2bf(v.x); o.y = f2bf(v.y); o.z = f2bf(v.z); o.w = f2bf(v.w);
    ((ushort4*)out)[i] = o;
}

// ---- CSR build: histogram by dst ----
__global__ __launch_bounds__(256) void hist_kernel(const int* __restrict__ ei,
                                                   int* __restrict__ deg) {
    int e = blockIdx.x * blockDim.x + threadIdx.x;
    if (e >= NE) return;
    atomicAdd(&deg[ei[NE + e]], 1);
}

// ---- single-block exclusive scan over deg[NN] -> row_start[NN+1], cur[NN] ----
__global__ __launch_bounds__(1024) void scan_kernel(const int* __restrict__ deg,
                                                    int* __restrict__ row_start,
                                                    int* __restrict__ cur) {
    __shared__ int part[1024];
    const int t = threadIdx.x;
    constexpr int C = (NN + 1023) / 1024;  // 10
    const int base = t * C;
    int sum = 0;
#pragma unroll
    for (int i = 0; i < C; i++) {
        int idx = base + i;
        if (idx < NN) sum += deg[idx];
    }
    part[t] = sum;
    __syncthreads();
    for (int off = 1; off < 1024; off <<= 1) {
        int v = (t >= off) ? part[t - off] : 0;
        __syncthreads();
        part[t] += v;
        __syncthreads();
    }
    int run = (t == 0) ? 0 : part[t - 1];
#pragma unroll
    for (int i = 0; i < C; i++) {
        int idx = base + i;
        if (idx < NN) {
            row_start[idx] = run;
            cur[idx] = run;
            run += deg[idx];
        }
    }
    if (t == 1023) row_start[NN] = run;
}

// ---- bucket-scatter edges into CSR order: one 8B record per edge ----
__global__ __launch_bounds__(256) void build_kernel(const int* __restrict__ ei,
                                                    const float* __restrict__ ew,
                                                    int* __restrict__ cur,
                                                    int2* __restrict__ erec) {
    int e = blockIdx.x * blockDim.x + threadIdx.x;
    if (e >= NE) return;
    int d = ei[NE + e];
    int pos = atomicAdd(&cur[d], 1);
    erec[pos] = make_int2(ei[e], __float_as_int(ew[e]));
}

// ---- aggregation via CSR gather (bf16 in/out, fp32 accumulate) ----
// out[n] = x[n] + sum_e w_e * x[src_e]
// One wave per node; 8-edge unroll with batched row loads for MLP.
template <int F>
__global__ __launch_bounds__(256) void gather_bf16_kernel(const int* __restrict__ row_start,
                                                          const int2* __restrict__ erec,
                                                          const ushort* __restrict__ x,
                                                          ushort* __restrict__ out) {
    constexpr int VEC = F / 64;  // bf16 per lane: 2 (F=128) or 4 (F=256)
    constexpr int U = 8;
    const int n = blockIdx.x * 4 + (threadIdx.x >> 6);
    const int lane = threadIdx.x & 63;
    if (n >= NN) return;
    const int beg = row_start[n];
    const int end = row_start[n + 1];
    const size_t loff = (size_t)lane * VEC;

    float acc[VEC];
    {
        ushort v[VEC];
        if (VEC == 4) *(ushort4*)v = *(const ushort4*)(x + (size_t)n * F + loff);
        else          *(ushort2*)v = *(const ushort2*)(x + (size_t)n * F + loff);
#pragma unroll
        for (int i = 0; i < VEC; i++) acc[i] = bf2f(v[i]);
    }

    int e = beg;
    for (; e + U <= end; e += U) {
        int2 rec[U];
#pragma unroll
        for (int u = 0; u < U; u++) rec[u] = erec[e + u];
        ushort v[U][VEC];
#pragma unroll
        for (int u = 0; u < U; u++) {
            const ushort* r = x + (size_t)rec[u].x * F + loff;
            if (VEC == 4) *(ushort4*)v[u] = *(const ushort4*)r;
            else          *(ushort2*)v[u] = *(const ushort2*)r;
        }
#pragma unroll
        for (int u = 0; u < U; u++) {
            const float w = __int_as_float(rec[u].y);
#pragma unroll
            for (int i = 0; i < VEC; i++) acc[i] += w * bf2f(v[u][i]);
        }
    }
    for (; e < end; e++) {
        int2 rec = erec[e];
        const float w = __int_as_float(rec.y);
        ushort v[VEC];
        if (VEC == 4) *(ushort4*)v = *(const ushort4*)(x + (size_t)rec.x * F + loff);
        else          *(ushort2*)v = *(const ushort2*)(x + (size_t)rec.x * F + loff);
#pragma unroll
        for (int i = 0; i < VEC; i++) acc[i] += w * bf2f(v[i]);
    }

    ushort o[VEC];
#pragma unroll
    for (int i = 0; i < VEC; i++) o[i] = f2bf(acc[i]);
    if (VEC == 4) *(ushort4*)(out + (size_t)n * F + loff) = *(ushort4*)o;
    else          *(ushort2*)(out + (size_t)n * F + loff) = *(ushort2*)o;
}

// ---- MFMA bf16 GEMM: C[M,256] = relu(A[M,K] @ W[256,K]^T + bias), bf16 out ----
// W is fp32 in global; converted to bf16 during LDS staging.
template <int K>
__global__ __launch_bounds__(256) void mfma_gemm_kernel(const ushort* __restrict__ A,
                                                        const float* __restrict__ W,
                                                        const float* __restrict__ bias,
                                                        ushort* __restrict__ C, int M) {
    constexpr int LDW = K + 8;
    __shared__ ushort Ws[64 * LDW];
    const int tid = threadIdx.x;
    const int bm = blockIdx.x * 128;
    const int bn = blockIdx.y * 64;

    constexpr int CPR = K / 4;
    for (int idx = tid; idx < 64 * CPR; idx += 256) {
        int r = idx / CPR, c = idx % CPR;
        float4 v = *(const float4*)(W + (size_t)(bn + r) * K + c * 4);
        ushort4 o;
        o.x = f2bf(v.x); o.y = f2bf(v.y); o.z = f2bf(v.z); o.w = f2bf(v.w);
        *(ushort4*)(&Ws[r * LDW + c * 4]) = o;
    }
    __syncthreads();

    const int wave = tid >> 6;
    const int lane = tid & 63;
    const int lrow = lane & 15;
    const int lq   = lane >> 4;
    const int m0 = bm + wave * 32;

    f32x4 acc[2][4] = {};
    const int r0 = min(m0 + lrow, M - 1);
    const int r1 = min(m0 + 16 + lrow, M - 1);

    for (int k0 = 0; k0 < K; k0 += 32) {
        const int kk = k0 + lq * 8;
        short8 a0 = *(const short8*)(A + (size_t)r0 * K + kk);
        short8 a1 = *(const short8*)(A + (size_t)r1 * K + kk);
        short8 b[4];
#pragma unroll
        for (int j = 0; j < 4; j++)
            b[j] = *(const short8*)(&Ws[(j * 16 + lrow) * LDW + kk]);
#pragma unroll
        for (int j = 0; j < 4; j++) {
            acc[0][j] = __builtin_amdgcn_mfma_f32_16x16x32_bf16(a0, b[j], acc[0][j], 0, 0, 0);
            acc[1][j] = __builtin_amdgcn_mfma_f32_16x16x32_bf16(a1, b[j], acc[1][j], 0, 0, 0);
        }
    }

#pragma unroll
    for (int sub = 0; sub < 2; sub++) {
#pragma unroll
        for (int j = 0; j < 4; j++) {
            const int gn = bn + j * 16 + lrow;
            const float bv = bias[gn];
#pragma unroll
            for (int i = 0; i < 4; i++) {
                const int gm = m0 + sub * 16 + lq * 4 + i;
                if (gm < M) {
                    float v = acc[sub][j][i] + bv;
                    v = fmaxf(v, 0.0f);
                    C[(size_t)gm * HIDC + gn] = f2bf(v);
                }
            }
        }
    }
}

__device__ __forceinline__ int lower_bound_batch(const int* __restrict__ batch, int val) {
    int lo = 0, hi = NN;
    while (lo < hi) {
        int mid = (lo + hi) >> 1;
        if (batch[mid] < val) lo = mid + 1;
        else hi = mid;
    }
    return lo;
}

// ---- segmented mean-pool stage 1: partial sums over bf16 h ----
__global__ __launch_bounds__(256) void pool_partial_kernel(const ushort* __restrict__ h,
                                                           const int* __restrict__ batch,
                                                           float* __restrict__ partials) {
    const int g = blockIdx.x;
    const int p = blockIdx.y;
    const int c = threadIdx.x;
    const int lo = lower_bound_batch(batch, g);
    const int hi = lower_bound_batch(batch, g + 1);
    const int cnt = hi - lo;
    const int chunk = (cnt + PP - 1) / PP;
    const int n0 = lo + p * chunk;
    const int n1 = min(hi, n0 + chunk);
    float sum = 0.0f;
    for (int n = n0; n < n1; n++) sum += bf2f(h[(size_t)n * HIDC + c]);
    partials[((size_t)g * PP + p) * HIDC + c] = sum;
}

// ---- stage 2: reduce partials, mean, head linear (fp32) ----
__global__ __launch_bounds__(256) void head_kernel(const float* __restrict__ partials,
                                                   const int* __restrict__ batch,
                                                   const float* __restrict__ Wl,
                                                   const float* __restrict__ bl,
                                                   float* __restrict__ out) {
    __shared__ float s[HIDC];
    const int g = blockIdx.x;
    const int c = threadIdx.x;
    const int lo = lower_bound_batch(batch, g);
    const int hi = lower_bound_batch(batch, g + 1);
    const float inv = 1.0f / fmaxf((float)(hi - lo), 1.0f);
    float sum = 0.0f;
#pragma unroll
    for (int p = 0; p < PP; p++) sum += partials[((size_t)g * PP + p) * HIDC + c];
    s[c] = sum * inv;
    __syncthreads();
    if (c < OUTC) {
        float acc = bl[c];
        for (int k = 0; k < HIDC; k++) acc += s[k] * Wl[(size_t)c * HIDC + k];
        out[(size_t)g * OUTC + c] = acc;
    }
}

extern "C" void kernel_launch(void* const* d_in, const int* in_sizes, int n_in,
                              void* d_out, int out_size, void* d_ws, size_t ws_size,
                              hipStream_t stream) {
    const float* x     = (const float*)d_in[0];
    const int*   ei    = (const int*)d_in[1];
    const int*   batch = (const int*)d_in[2];
    const float* ew    = (const float*)d_in[3];
    const float* W1    = (const float*)d_in[4];
    const float* b1    = (const float*)d_in[5];
    const float* W2    = (const float*)d_in[6];
    const float* b2    = (const float*)d_in[7];
    const float* W3    = (const float*)d_in[8];
    const float* b3    = (const float*)d_in[9];
    const float* Wl    = (const float*)d_in[10];
    const float* bl    = (const float*)d_in[11];

    // ---- workspace layout ----
    char* p = (char*)d_ws;
    ushort* xb     = (ushort*)p; p += (size_t)NN * INC * 2;
    ushort* agg128 = (ushort*)p; p += (size_t)NN * INC * 2;
    ushort* agg256 = (ushort*)p; p += (size_t)NN * HIDC * 2;
    ushort* h      = (ushort*)p; p += (size_t)NN * HIDC * 2;
    int2*   erec   = (int2*)p;   p += (size_t)NE * 8;
    float*  partials = (float*)p; p += (size_t)NG * PP * HIDC * 4;
    int*    deg    = (int*)p;    p += (size_t)NN * 4;
    int*    row_start = (int*)p; p += 40016;
    int*    cur    = (int*)p;    p += (size_t)NN * 4;

    // ---- CSR build (per call) ----
    zero_i_kernel<<<(NN + 255) / 256, 256, 0, stream>>>(deg, NN);
    hist_kernel<<<(NE + 255) / 256, 256, 0, stream>>>(ei, deg);
    scan_kernel<<<1, 1024, 0, stream>>>(deg, row_start, cur);
    build_kernel<<<(NE + 255) / 256, 256, 0, stream>>>(ei, ew, cur, erec);

    // ---- x -> bf16 ----
    f2bf_kernel<<<(NN * INC / 4 + 255) / 256, 256, 0, stream>>>(x, xb, NN * INC / 4);

    const int gather_grid = (NN + 3) / 4;
    dim3 gemm_grid((NN + 127) / 128, HIDC / 64);

    // ---- layer 1 (K=128) ----
    gather_bf16_kernel<INC><<<gather_grid, 256, 0, stream>>>(row_start, erec, xb, agg128);
    mfma_gemm_kernel<INC><<<gemm_grid, 256, 0, stream>>>(agg128, W1, b1, h, NN);

    // ---- layer 2 (K=256) ----
    gather_bf16_kernel<HIDC><<<gather_grid, 256, 0, stream>>>(row_start, erec, h, agg256);
    mfma_gemm_kernel<HIDC><<<gemm_grid, 256, 0, stream>>>(agg256, W2, b2, h, NN);

    // ---- layer 3 (K=256) ----
    gather_bf16_kernel<HIDC><<<gather_grid, 256, 0, stream>>>(row_start, erec, h, agg256);
    mfma_gemm_kernel<HIDC><<<gemm_grid, 256, 0, stream>>>(agg256, W3, b3, h, NN);

    // ---- global mean pool + head ----
    pool_partial_kernel<<<dim3(NG, PP), 256, 0, stream>>>(h, batch, partials);
    head_kernel<<<NG, 256, 0, stream>>>(partials, batch, Wl, bl, (float*)d_out);
}